// Round 2
// baseline (2480.749 us; speedup 1.0000x reference)
//
#include <hip/hip_runtime.h>
#include <cstdint>

#define DEVI __device__ __forceinline__

#define NEGC  (-1.0e9f)
#define NEGID (-2.0e9f)

// ---------- helpers ----------
DEVI float lse2f(float p, float q){
  float m = fmaxf(p, q);
  return m + __logf(__expf(p - m) + __expf(q - m));
}
DEVI float lse3f(float a, float b, float c){
  float m = fmaxf(fmaxf(a, b), c);
  return m + __logf(__expf(a - m) + __expf(b - m) + __expf(c - m));
}

// raw barrier: wait only LDS ops, do NOT drain vmcnt (keeps global_load_lds
// prefetch in flight across mid-row barriers)
DEVI void bar_raw(){
  asm volatile("s_waitcnt lgkmcnt(0)" ::: "memory");
  __builtin_amdgcn_s_barrier();
  asm volatile("" ::: "memory");
}
// full barrier: drain everything (end of row: prefetch must have landed)
DEVI void bar_full(){
  asm volatile("s_waitcnt vmcnt(0) lgkmcnt(0)" ::: "memory");
  __builtin_amdgcn_s_barrier();
  asm volatile("" ::: "memory");
}

DEVI void gld_lds16(const float* g, float* l){
  __builtin_amdgcn_global_load_lds(
    (const __attribute__((address_space(1))) unsigned int*)(uintptr_t)g,
    (__attribute__((address_space(3))) unsigned int*)(uintptr_t)l,
    16, 0, 0);
}
// stage nchunks * 1024B from g into LDS l, spread over 8 waves.
// LDS dest for each chunk is wave-uniform base; HW adds lane*16.
DEVI void stage8(const float* g, float* l, int nchunks, int wid, int lane){
  for (int c = wid; c < nchunks; c += 8)
    gld_lds16(g + (size_t)c*256 + lane*4, l + (size_t)c*256);
}

// ---------- GEMM: theta[b][i][s][j] = sum_d zx[b,i,d,s]*zy[b,j,d,s] ----------
// 64x64 tile, 256 threads, 4x4 micro-tile, K-chunk 16, LDS layout [d][s][64]
__global__ __launch_bounds__(256) void k_gemm_th(
    const float* __restrict__ zx, const float* __restrict__ zy, float* __restrict__ th){
  const int b  = blockIdx.z;
  const int i0 = blockIdx.y * 64, j0 = blockIdx.x * 64;
  const int tid = threadIdx.x;
  const int tx = tid & 15, ty = tid >> 4;
  __shared__ __align__(16) float xs[16*3*64];
  __shared__ __align__(16) float ys[16*3*64];
  const float* xb = zx + ((size_t)b*512 + i0) * 768;
  const float* yb = zy + ((size_t)b*512 + j0) * 768;
  float acc[3][4][4] = {};
  for (int k = 0; k < 256; k += 16) {
    #pragma unroll
    for (int p = 0; p < 3; ++p) {
      int q = tid + p*256;         // 0..767 float4s
      int row = q / 12, f4 = q % 12;
      float4 xv = *(const float4*)(xb + (size_t)row*768 + k*3 + f4*4);
      float4 yv = *(const float4*)(yb + (size_t)row*768 + k*3 + f4*4);
      const float* xe = (const float*)&xv;
      const float* ye = (const float*)&yv;
      #pragma unroll
      for (int e = 0; e < 4; ++e) {
        int idx = f4*4 + e;        // = d*3+s, 0..47
        xs[idx*64 + row] = xe[e];
        ys[idx*64 + row] = ye[e];
      }
    }
    __syncthreads();
    #pragma unroll
    for (int dd = 0; dd < 16; ++dd) {
      float4 xa[3], yv2[3];
      #pragma unroll
      for (int s = 0; s < 3; ++s) {
        xa[s]  = *(const float4*)&xs[(dd*3 + s)*64 + ty*4];
        yv2[s] = *(const float4*)&ys[(dd*3 + s)*64 + tx*4];
      }
      #pragma unroll
      for (int s = 0; s < 3; ++s)
        #pragma unroll
        for (int a2 = 0; a2 < 4; ++a2)
          #pragma unroll
          for (int c = 0; c < 4; ++c)
            acc[s][a2][c] += ((const float*)&xa[s])[a2] * ((const float*)&yv2[s])[c];
    }
    __syncthreads();
  }
  #pragma unroll
  for (int s = 0; s < 3; ++s)
    #pragma unroll
    for (int a2 = 0; a2 < 4; ++a2) {
      float4 v = make_float4(acc[s][a2][0], acc[s][a2][1], acc[s][a2][2], acc[s][a2][3]);
      *(float4*)(th + (((size_t)b*512 + i0 + ty*4 + a2)*3 + s)*512 + j0 + tx*4) = v;
    }
}

// ---------- GEMM: A[b][i][v][u][j] = sum_d gx[b,i,d,u]*gy[b,j,d,v] ----------
// 32x32 tile, 256 threads, 2x2 micro-tile x 9 (u,v), K-chunk 32, LDS [d][u][32]
__global__ __launch_bounds__(256) void k_gemm_A(
    const float* __restrict__ gx, const float* __restrict__ gy, float* __restrict__ Ag){
  const int b  = blockIdx.z;
  const int i0 = blockIdx.y * 32, j0 = blockIdx.x * 32;
  const int tid = threadIdx.x;
  const int tx = tid & 15, ty = tid >> 4;
  __shared__ __align__(16) float xs[32*3*32];
  __shared__ __align__(16) float ys[32*3*32];
  const float* xb = gx + ((size_t)b*512 + i0) * 768;
  const float* yb = gy + ((size_t)b*512 + j0) * 768;
  float acc[3][3][2][2] = {};
  for (int k = 0; k < 256; k += 32) {
    #pragma unroll
    for (int p = 0; p < 3; ++p) {
      int q = tid + p*256;
      int row = q / 24, f4 = q % 24;
      float4 xv = *(const float4*)(xb + (size_t)row*768 + k*3 + f4*4);
      float4 yv = *(const float4*)(yb + (size_t)row*768 + k*3 + f4*4);
      const float* xe = (const float*)&xv;
      const float* ye = (const float*)&yv;
      #pragma unroll
      for (int e = 0; e < 4; ++e) {
        int idx = f4*4 + e;        // = d*3+u, 0..95
        xs[idx*32 + row] = xe[e];
        ys[idx*32 + row] = ye[e];
      }
    }
    __syncthreads();
    #pragma unroll
    for (int dd = 0; dd < 32; ++dd) {
      float2 ga[3], gb[3];
      #pragma unroll
      for (int u = 0; u < 3; ++u) ga[u] = *(const float2*)&xs[(dd*3 + u)*32 + ty*2];
      #pragma unroll
      for (int v = 0; v < 3; ++v) gb[v] = *(const float2*)&ys[(dd*3 + v)*32 + tx*2];
      #pragma unroll
      for (int u = 0; u < 3; ++u)
        #pragma unroll
        for (int v = 0; v < 3; ++v) {
          acc[u][v][0][0] += ga[u].x * gb[v].x;
          acc[u][v][0][1] += ga[u].x * gb[v].y;
          acc[u][v][1][0] += ga[u].y * gb[v].x;
          acc[u][v][1][1] += ga[u].y * gb[v].y;
        }
    }
    __syncthreads();
  }
  #pragma unroll
  for (int u = 0; u < 3; ++u)
    #pragma unroll
    for (int v = 0; v < 3; ++v)
      #pragma unroll
      for (int a2 = 0; a2 < 2; ++a2) {
        float2 w; w.x = acc[u][v][a2][0]; w.y = acc[u][v][a2][1];
        *(float2*)(Ag + ((((size_t)b*512 + i0 + ty*2 + a2)*3 + v)*3 + u)*512 + j0 + tx*2) = w;
      }
}

// ---------- forward DP ----------
// one block per batch, 512 threads (thread tid <-> column j = tid+1)
// V rows in LDS [3][513] (col 0 = boundary NEG); theta/A rows double-buffered
// via global_load_lds; y-state via log-domain inclusive scan.
__global__ __launch_bounds__(512) void k_fwd(
    const float* __restrict__ th, const float* __restrict__ Ag,
    float* __restrict__ V, float* __restrict__ score){
  const int b = blockIdx.x;
  const int tid = threadIdx.x;
  const int lane = tid & 63, wid = tid >> 6;
  __shared__ __align__(16) float th_s[2][1536];
  __shared__ __align__(16) float A_s[2][4608];
  __shared__ float Vbuf[2][3*513];
  __shared__ float wag[8][2];
  const float* thb = th + (size_t)b * 512 * 1536;
  const float* Ab  = Ag + (size_t)b * 512 * 4608;
  float*       Vb  = V  + (size_t)b * 512 * 1536;

  for (int kk = tid; kk < 2*3*513; kk += 512) (&Vbuf[0][0])[kk] = NEGC;
  __syncthreads();
  if (tid == 0) Vbuf[0][0] = 0.f;              // V[0][0][m] = 0
  stage8(thb, th_s[0], 6, wid, lane);
  stage8(Ab,  A_s[0], 18, wid, lane);
  bar_full();

  int pv = 0;
  for (int i = 1; i <= 512; ++i) {
    const int bc = (i - 1) & 1;
    if (i < 512) {
      stage8(thb + (size_t)i*1536, th_s[i & 1], 6, wid, lane);
      stage8(Ab  + (size_t)i*4608, A_s[i & 1], 18, wid, lane);
    }
    const float* ths = th_s[bc];
    const float* As  = A_s[bc];
    float* Vp = Vbuf[pv];
    float* Vc = Vbuf[pv ^ 1];
    const int tj = tid, j = tid + 1;

    float thm = ths[tj], thx = ths[512 + tj], thy = ths[1024 + tj];
    float vd0 = Vp[tj],     vd1 = Vp[513 + tj],     vd2 = Vp[2*513 + tj];
    float vu0 = Vp[tj + 1], vu1 = Vp[513 + tj + 1], vu2 = Vp[2*513 + tj + 1];
    float Vm = thm + lse3f(vd0 + As[tj],        vd1 + As[512 + tj],  vd2 + As[1024 + tj]);
    float Vx = thx + lse3f(vu0 + As[1536 + tj], vu1 + As[2048 + tj], vu2 + As[2560 + tj]);
    Vc[j] = Vm; Vc[513 + j] = Vx;
    if (tid == 0) { Vc[0] = NEGC; Vc[513] = NEGC; Vc[2*513] = NEGC; }
    bar_raw();
    float Vml = Vc[tj];          // Vm[j-1] (NEG at j=1)
    float Vxl = Vc[513 + tj];
    float a  = As[4096 + tj] + thy;                               // A[2][2] + th_y
    float bb = thy + lse2f(Vml + As[3072 + tj], Vxl + As[3584 + tj]);
    // inclusive scan (log-affine): combine((a1,b1),(a2,b2)) = (a1+a2, lse(b1+a2, b2))
    #pragma unroll
    for (int st = 1; st < 64; st <<= 1) {
      float ao = __shfl_up(a,  st, 64);
      float bo = __shfl_up(bb, st, 64);
      if (lane >= st) { bb = lse2f(bo + a, bb); a += ao; }
    }
    if (lane == 63) { wag[wid][0] = a; wag[wid][1] = bb; }
    bar_raw();
    float pb = NEGID;
    for (int w = 0; w < wid; ++w) pb = lse2f(pb + wag[w][0], wag[w][1]);
    float Vy = lse2f(pb + a, bb);
    Vc[2*513 + j] = Vy;
    float* Vr = Vb + (size_t)(i - 1) * 1536;
    Vr[tj] = Vm; Vr[512 + tj] = Vx; Vr[1024 + tj] = Vy;
    bar_full();
    pv ^= 1;
  }
  if (tid == 0) {
    float* Vl = Vbuf[pv];
    score[b] = lse3f(Vl[512], Vl[513 + 512], Vl[2*513 + 512]);
  }
}

// ---------- backward DP (adjoint) ----------
// E[i][j][u] = sum over successors of E_succ * exp(V[i][j][u] + A + th_succ - V_succ)
// (all weights <= 1 for real cells). In-row y-adjoint: E_y[j] = c[j] + r[j]*E_y[j+1]
// -> affine reverse scan. 3-slot rotation of theta/A/V row buffers.
__global__ __launch_bounds__(512) void k_bwd(
    const float* __restrict__ th, const float* __restrict__ Ag,
    const float* __restrict__ V, const float* __restrict__ score,
    float* __restrict__ out){
  const int b = blockIdx.x;
  const int tid = threadIdx.x;
  const int lane = tid & 63, wid = tid >> 6;
  __shared__ __align__(16) float th_s[3][1536];
  __shared__ __align__(16) float A_s[3][4608];
  __shared__ __align__(16) float Vls[3][1536];
  __shared__ float Eb[2][3*514];   // [s][jcol 0..513]; cols 0 & 513 stay 0 (pads)
  __shared__ float wag[8][2];
  const float* thb = th + (size_t)b * 512 * 1536;
  const float* Ab  = Ag + (size_t)b * 512 * 4608;
  const float* Vb  = V  + (size_t)b * 512 * 1536;
  float* ob = out + (size_t)b * 512 * 512 * 3;

  for (int kk = tid; kk < 2*3*514; kk += 512) (&Eb[0][0])[kk] = 0.f;
  // initial: theta/A row ti=511 -> slot 511%3=1 ; V row 512 -> slot 512%3=2
  stage8(thb + (size_t)511*1536, th_s[1], 6, wid, lane);
  stage8(Ab  + (size_t)511*4608, A_s[1], 18, wid, lane);
  stage8(Vb  + (size_t)511*1536, Vls[2], 6, wid, lane);
  float sc = score[b];
  bar_full();

  int ce = 0;
  for (int i = 512; i >= 1; --i) {
    if (i >= 2) {   // prefetch for next iteration: theta/A row ti=i-2, V row i-1
      stage8(thb + (size_t)(i-2)*1536, th_s[(i-2)%3], 6, wid, lane);
      stage8(Ab  + (size_t)(i-2)*4608, A_s[(i-2)%3], 18, wid, lane);
      stage8(Vb  + (size_t)(i-2)*1536, Vls[(i-1)%3], 6, wid, lane);
    }
    const float* thN = th_s[(i-1)%3];  // row ti=i-1 (for in-row y successor)
    const float* AN  = A_s[(i-1)%3];
    const float* thK = th_s[i%3];      // row ti=i   (for next-row successors; valid iff i<512)
    const float* AK  = A_s[i%3];
    const float* Vc  = Vls[i%3];       // V row i
    const float* Vn  = Vls[(i+1)%3];   // V row i+1 (garbage-gated at i=512)
    const float* E1  = Eb[ce ^ 1];     // E row i+1
    float* Ec = Eb[ce];
    const int tj = tid;
    const bool hasN = (i < 512);
    const bool hasJ = (tid < 511);
    const int  c1 = hasJ ? tid + 1 : tid;   // clamped successor column

    float v0 = Vc[tj], v1 = Vc[512 + tj], v2 = Vc[1024 + tj];
    float vyr = hasJ ? Vc[1024 + c1] : 0.f;   // V[i][j+1][y]
    float vnm = Vn[c1];                       // V[i+1][j+1][m]
    float vnx = Vn[512 + tj];                 // V[i+1][j][x]
    float e1m = E1[tid + 2];                  // E[i+1][j+1][m]
    float e1x = E1[514 + tid + 1];            // E[i+1][j][x]
    float thT1 = thK[c1], thT2 = thK[512 + tj], thT3 = thN[1024 + c1];

    float w;
    w = (hasN && hasJ) ? e1m * __expf(v0 + AK[c1]       + thT1 - vnm) : 0.f;
    float D0 = w + (hasN ? e1x * __expf(v0 + AK[1536 + tj] + thT2 - vnx) : 0.f);
    // NOTE: wy* MUST be hasJ-gated: at the clamped boundary the exp argument is
    // V + A + th - 0 ~ +500 -> inf, and inf * (EyR pad = 0) = NaN in the output.
    float wy0 = hasJ ? __expf(v0 + AN[3072 + c1] + thT3 - vyr) : 0.f;
    w = (hasN && hasJ) ? e1m * __expf(v1 + AK[512 + c1] + thT1 - vnm) : 0.f;
    float D1 = w + (hasN ? e1x * __expf(v1 + AK[2048 + tj] + thT2 - vnx) : 0.f);
    float wy1 = hasJ ? __expf(v1 + AN[3584 + c1] + thT3 - vyr) : 0.f;
    w = (hasN && hasJ) ? e1m * __expf(v2 + AK[1024 + c1] + thT1 - vnm) : 0.f;
    float D2 = w + (hasN ? e1x * __expf(v2 + AK[2560 + tj] + thT2 - vnx) : 0.f);
    float wy2 = hasJ ? __expf(v2 + AN[4096 + c1] + thT3 - vyr) : 0.f;

    if (i == 512 && tid == 511) {   // terminal softmax seeds the adjoint
      D0 = __expf(v0 - sc); D1 = __expf(v1 - sc); D2 = __expf(v2 - sc);
    }

    // reverse affine scan: E_y[j] = c[j] + r[j]*E_y[j+1]
    float ra = wy2;
    float ca = D2;
    #pragma unroll
    for (int st = 1; st < 64; st <<= 1) {
      float ro = __shfl_down(ra, st, 64);
      float co = __shfl_down(ca, st, 64);
      if (lane + st < 64) { ca = ca + ra * co; ra = ra * ro; }
    }
    if (lane == 0) { wag[wid][0] = ra; wag[wid][1] = ca; }
    bar_raw();
    float sr = 1.f, sc2 = 0.f;
    for (int w2 = wid + 1; w2 < 8; ++w2) { sc2 = sc2 + sr * wag[w2][1]; sr = sr * wag[w2][0]; }
    float Ey = ca + ra * sc2;
    Ec[2*514 + tid + 1] = Ey;
    bar_raw();
    float EyR = Ec[2*514 + tid + 2];   // E_y[j+1] (pad 0 at j=M)
    float Em = D0 + wy0 * EyR;
    float Ex = D1 + wy1 * EyR;
    Ec[tid + 1] = Em;
    Ec[514 + tid + 1] = Ex;
    float* o = ob + ((size_t)(i - 1) * 512 + tj) * 3;
    o[0] = Em; o[1] = Ex; o[2] = Ey;
    bar_full();
    ce ^= 1;
  }
}

// ---------- launch ----------
extern "C" void kernel_launch(void* const* d_in, const int* in_sizes, int n_in,
                              void* d_out, int out_size, void* d_ws, size_t ws_size,
                              hipStream_t stream) {
  const float* zx = (const float*)d_in[0];
  const float* zy = (const float*)d_in[1];
  const float* gx = (const float*)d_in[2];
  const float* gy = (const float*)d_in[3];
  float* ws = (float*)d_ws;
  float* th = ws;                       // [8][512][3][512]   = 6,291,456 f
  float* Ag = ws + 6291456;             // [8][512][3v][3u][512] = 18,874,368 f
  float* V  = ws + 25165824;            // [8][512][3][512]   = 6,291,456 f
  float* sc = ws + 31457280;            // [8]
  float* out = (float*)d_out;           // [8][512][512][3]

  k_gemm_th<<<dim3(8, 8, 8),   256, 0, stream>>>(zx, zy, th);
  k_gemm_A <<<dim3(16, 16, 8), 256, 0, stream>>>(gx, gy, Ag);
  k_fwd<<<8, 512, 0, stream>>>(th, Ag, V, sc);
  k_bwd<<<8, 512, 0, stream>>>(th, Ag, V, sc, out);
}

// Round 6
// 2406.187 us; speedup vs baseline: 1.0310x; 1.0310x over previous
//
#include <hip/hip_runtime.h>
#include <cstdint>

#define DEVI __device__ __forceinline__

#define NEGC  (-1.0e9f)
#define NEGID (-2.0e9f)

// ---------- helpers ----------
DEVI float lse2f(float p, float q){
  float m = fmaxf(p, q);
  return m + __logf(__expf(p - m) + __expf(q - m));
}
DEVI float lse3f(float a, float b, float c){
  float m = fmaxf(fmaxf(a, b), c);
  return m + __logf(__expf(a - m) + __expf(b - m) + __expf(c - m));
}

// raw barrier: wait only LDS ops, do NOT drain vmcnt (keeps global_load_lds
// prefetch in flight across mid-row barriers)
DEVI void bar_raw(){
  asm volatile("s_waitcnt lgkmcnt(0)" ::: "memory");
  __builtin_amdgcn_s_barrier();
  asm volatile("" ::: "memory");
}
// full barrier: drain everything (end of row: prefetch must have landed).
// Global stores are issued at the TOP of each row, so their acks are long
// since retired by the time this drain runs.
DEVI void bar_full(){
  asm volatile("s_waitcnt vmcnt(0) lgkmcnt(0)" ::: "memory");
  __builtin_amdgcn_s_barrier();
  asm volatile("" ::: "memory");
}

DEVI void gld_lds16(const float* g, float* l){
  __builtin_amdgcn_global_load_lds(
    (const __attribute__((address_space(1))) unsigned int*)(uintptr_t)g,
    (__attribute__((address_space(3))) unsigned int*)(uintptr_t)l,
    16, 0, 0);
}
// stage nchunks * 1024B from g into LDS l, spread over 8 waves.
DEVI void stage8(const float* g, float* l, int nchunks, int wid, int lane){
  for (int c = wid; c < nchunks; c += 8)
    gld_lds16(g + (size_t)c*256 + lane*4, l + (size_t)c*256);
}

// ---------- GEMM: theta[b][i][s][j] = sum_d zx[b,i,d,s]*zy[b,j,d,s] (LOG) ----------
__global__ __launch_bounds__(256) void k_gemm_th(
    const float* __restrict__ zx, const float* __restrict__ zy, float* __restrict__ th){
  const int b  = blockIdx.z;
  const int i0 = blockIdx.y * 64, j0 = blockIdx.x * 64;
  const int tid = threadIdx.x;
  const int tx = tid & 15, ty = tid >> 4;
  __shared__ __align__(16) float xs[16*3*64];
  __shared__ __align__(16) float ys[16*3*64];
  const float* xb = zx + ((size_t)b*512 + i0) * 768;
  const float* yb = zy + ((size_t)b*512 + j0) * 768;
  float acc[3][4][4] = {};
  for (int k = 0; k < 256; k += 16) {
    #pragma unroll
    for (int p = 0; p < 3; ++p) {
      int q = tid + p*256;
      int row = q / 12, f4 = q % 12;
      float4 xv = *(const float4*)(xb + (size_t)row*768 + k*3 + f4*4);
      float4 yv = *(const float4*)(yb + (size_t)row*768 + k*3 + f4*4);
      const float* xe = (const float*)&xv;
      const float* ye = (const float*)&yv;
      #pragma unroll
      for (int e = 0; e < 4; ++e) {
        int idx = f4*4 + e;
        xs[idx*64 + row] = xe[e];
        ys[idx*64 + row] = ye[e];
      }
    }
    __syncthreads();
    #pragma unroll
    for (int dd = 0; dd < 16; ++dd) {
      float4 xa[3], yv2[3];
      #pragma unroll
      for (int s = 0; s < 3; ++s) {
        xa[s]  = *(const float4*)&xs[(dd*3 + s)*64 + ty*4];
        yv2[s] = *(const float4*)&ys[(dd*3 + s)*64 + tx*4];
      }
      #pragma unroll
      for (int s = 0; s < 3; ++s)
        #pragma unroll
        for (int a2 = 0; a2 < 4; ++a2)
          #pragma unroll
          for (int c = 0; c < 4; ++c)
            acc[s][a2][c] += ((const float*)&xa[s])[a2] * ((const float*)&yv2[s])[c];
    }
    __syncthreads();
  }
  #pragma unroll
  for (int s = 0; s < 3; ++s)
    #pragma unroll
    for (int a2 = 0; a2 < 4; ++a2) {
      float4 v = make_float4(acc[s][a2][0], acc[s][a2][1], acc[s][a2][2], acc[s][a2][3]);
      *(float4*)(th + (((size_t)b*512 + i0 + ty*4 + a2)*3 + s)*512 + j0 + tx*4) = v;
    }
}

// ---------- GEMM: A[b][i][v][u][j] = sum_d gx[b,i,d,u]*gy[b,j,d,v] (LOG) ----------
__global__ __launch_bounds__(256) void k_gemm_A(
    const float* __restrict__ gx, const float* __restrict__ gy, float* __restrict__ Ag){
  const int b  = blockIdx.z;
  const int i0 = blockIdx.y * 32, j0 = blockIdx.x * 32;
  const int tid = threadIdx.x;
  const int tx = tid & 15, ty = tid >> 4;
  __shared__ __align__(16) float xs[32*3*32];
  __shared__ __align__(16) float ys[32*3*32];
  const float* xb = gx + ((size_t)b*512 + i0) * 768;
  const float* yb = gy + ((size_t)b*512 + j0) * 768;
  float acc[3][3][2][2] = {};
  for (int k = 0; k < 256; k += 32) {
    #pragma unroll
    for (int p = 0; p < 3; ++p) {
      int q = tid + p*256;
      int row = q / 24, f4 = q % 24;
      float4 xv = *(const float4*)(xb + (size_t)row*768 + k*3 + f4*4);
      float4 yv = *(const float4*)(yb + (size_t)row*768 + k*3 + f4*4);
      const float* xe = (const float*)&xv;
      const float* ye = (const float*)&yv;
      #pragma unroll
      for (int e = 0; e < 4; ++e) {
        int idx = f4*4 + e;
        xs[idx*32 + row] = xe[e];
        ys[idx*32 + row] = ye[e];
      }
    }
    __syncthreads();
    #pragma unroll
    for (int dd = 0; dd < 32; ++dd) {
      float2 ga[3], gb[3];
      #pragma unroll
      for (int u = 0; u < 3; ++u) ga[u] = *(const float2*)&xs[(dd*3 + u)*32 + ty*2];
      #pragma unroll
      for (int v = 0; v < 3; ++v) gb[v] = *(const float2*)&ys[(dd*3 + v)*32 + tx*2];
      #pragma unroll
      for (int u = 0; u < 3; ++u)
        #pragma unroll
        for (int v = 0; v < 3; ++v) {
          acc[u][v][0][0] += ga[u].x * gb[v].x;
          acc[u][v][0][1] += ga[u].x * gb[v].y;
          acc[u][v][1][0] += ga[u].y * gb[v].x;
          acc[u][v][1][1] += ga[u].y * gb[v].y;
        }
    }
    __syncthreads();
  }
  #pragma unroll
  for (int u = 0; u < 3; ++u)
    #pragma unroll
    for (int v = 0; v < 3; ++v)
      #pragma unroll
      for (int a2 = 0; a2 < 2; ++a2) {
        float2 w; w.x = acc[u][v][a2][0]; w.y = acc[u][v][a2][1];
        *(float2*)(Ag + ((((size_t)b*512 + i0 + ty*2 + a2)*3 + v)*3 + u)*512 + j0 + tx*2) = w;
      }
}

// ---------- forward DP (log space; round-2 math; 2 barriers/row) ----------
// Left neighbors via shfl_up + lane-0 bit-identical recompute (barrier 1 gone);
// V-row global stores deferred to next iteration's top.
__global__ __launch_bounds__(512) void k_fwd(
    const float* __restrict__ th, const float* __restrict__ Ag,
    float* __restrict__ V, float* __restrict__ score){
  const int b = blockIdx.x;
  const int tid = threadIdx.x;
  const int lane = tid & 63, wid = tid >> 6;
  __shared__ __align__(16) float th_s[2][1536];
  __shared__ __align__(16) float A_s[2][4608];
  __shared__ float Vbuf[2][3*513];
  __shared__ __align__(8) float wag[8][2];
  const float* thb = th + (size_t)b * 512 * 1536;
  const float* Ab  = Ag + (size_t)b * 512 * 4608;
  float*       Vb  = V  + (size_t)b * 512 * 1536;

  for (int kk = tid; kk < 2*3*513; kk += 512) (&Vbuf[0][0])[kk] = NEGC;
  __syncthreads();
  if (tid == 0) Vbuf[0][0] = 0.f;              // V[0][0][m] = 0
  stage8(thb, th_s[0], 6, wid, lane);
  stage8(Ab,  A_s[0], 18, wid, lane);
  bar_full();

  float pVm = NEGC, pVx = NEGC, pVy = NEGC;    // deferred row store
  int pv = 0;
  for (int i = 1; i <= 512; ++i) {
    // deferred store of row i-1 (issued first: ack retires during this row)
    if (i > 1) {
      float* Vr = Vb + (size_t)(i - 2) * 1536;
      Vr[tid] = pVm; Vr[512 + tid] = pVx; Vr[1024 + tid] = pVy;
    }
    if (i < 512) {
      stage8(thb + (size_t)i*1536, th_s[i & 1], 6, wid, lane);
      stage8(Ab  + (size_t)i*4608, A_s[i & 1], 18, wid, lane);
    }
    const float* ths = th_s[(i - 1) & 1];
    const float* As  = A_s[(i - 1) & 1];
    float* Vp = Vbuf[pv];
    float* Vc = Vbuf[pv ^ 1];
    const int tj = tid, j = tid + 1;

    float vd0 = Vp[tj],     vd1 = Vp[513 + tj],     vd2 = Vp[2*513 + tj];
    float vu0 = Vp[tj + 1], vu1 = Vp[513 + tj + 1], vu2 = Vp[2*513 + tj + 1];
    float Vm = ths[tj]       + lse3f(vd0 + As[tj],        vd1 + As[512 + tj],  vd2 + As[1024 + tj]);
    float Vx = ths[512 + tj] + lse3f(vu0 + As[1536 + tj], vu1 + As[2048 + tj], vu2 + As[2560 + tj]);
    // left neighbors without a barrier: shfl within wave; lane 0 recomputes
    // its left column with the bit-identical expression from LDS.
    float Vml = __shfl_up(Vm, 1, 64);
    float Vxl = __shfl_up(Vx, 1, 64);
    if (lane == 0) {
      if (tid == 0) { Vml = NEGC; Vxl = NEGC; }
      else {
        int q = tj - 1;
        float e0 = Vp[q], e1 = Vp[513 + q], e2 = Vp[2*513 + q];
        float f0 = Vp[q + 1], f1 = Vp[513 + q + 1], f2 = Vp[2*513 + q + 1];
        Vml = ths[q]       + lse3f(e0 + As[q],        e1 + As[512 + q],  e2 + As[1024 + q]);
        Vxl = ths[512 + q] + lse3f(f0 + As[1536 + q], f1 + As[2048 + q], f2 + As[2560 + q]);
      }
    }
    Vc[j] = Vm; Vc[513 + j] = Vx;
    if (tid == 0) { Vc[0] = NEGC; Vc[513] = NEGC; Vc[2*513] = NEGC; }
    float thy = ths[1024 + tj];
    float a  = As[4096 + tj] + thy;                               // A22 + th_y
    float bb = thy + lse2f(Vml + As[3072 + tj], Vxl + As[3584 + tj]);
    // log-affine inclusive scan: combine((a1,b1),(a2,b2)) = (a1+a2, lse(b1+a2, b2))
    #pragma unroll
    for (int st = 1; st < 64; st <<= 1) {
      float ao = __shfl_up(a,  st, 64);
      float bo = __shfl_up(bb, st, 64);
      if (lane >= st) { bb = lse2f(bo + a, bb); a += ao; }
    }
    if (lane == 63) { wag[wid][0] = a; wag[wid][1] = bb; }
    bar_raw();
    float pb = NEGID;
    for (int w = 0; w < wid; ++w) pb = lse2f(pb + wag[w][0], wag[w][1]);
    float Vy = lse2f(pb + a, bb);
    Vc[2*513 + j] = Vy;
    pVm = Vm; pVx = Vx; pVy = Vy;
    bar_full();
    pv ^= 1;
  }
  // final row store + terminal score (col 512 = tid 511's registers)
  float* Vr = Vb + (size_t)511 * 1536;
  Vr[tid] = pVm; Vr[512 + tid] = pVx; Vr[1024 + tid] = pVy;
  if (tid == 511) score[b] = lse3f(pVm, pVx, pVy);
}

// ---------- backward DP (round-2 math; 2 barriers/row) ----------
// E_y[j+1] via shfl_down suffix identity (y-plane barrier gone); out stores
// deferred to next iteration's top.
__global__ __launch_bounds__(512) void k_bwd(
    const float* __restrict__ th, const float* __restrict__ Ag,
    const float* __restrict__ V, const float* __restrict__ score,
    float* __restrict__ out){
  const int b = blockIdx.x;
  const int tid = threadIdx.x;
  const int lane = tid & 63, wid = tid >> 6;
  __shared__ __align__(16) float th_s[3][1536];
  __shared__ __align__(16) float A_s[3][4608];
  __shared__ __align__(16) float Vls[3][1536];
  __shared__ float Eb[2][2*514];   // [m/x][col 0..513]; pads stay 0
  __shared__ __align__(8) float wag[8][2];
  const float* thb = th + (size_t)b * 512 * 1536;
  const float* Ab  = Ag + (size_t)b * 512 * 4608;
  const float* Vb  = V  + (size_t)b * 512 * 1536;
  float* ob = out + (size_t)b * 512 * 512 * 3;

  for (int kk = tid; kk < 2*2*514; kk += 512) (&Eb[0][0])[kk] = 0.f;
  // initial: theta/A row ti=511 -> slot 511%3=1 ; V row 512 -> slot 512%3=2
  stage8(thb + (size_t)511*1536, th_s[1], 6, wid, lane);
  stage8(Ab  + (size_t)511*4608, A_s[1], 18, wid, lane);
  stage8(Vb  + (size_t)511*1536, Vls[2], 6, wid, lane);
  float sc = score[b];
  bar_full();

  float pEm = 0.f, pEx = 0.f, pEy = 0.f;    // deferred out store
  int ce = 0;
  for (int i = 512; i >= 1; --i) {
    // deferred out store of row i (computed last iteration)
    if (i < 512) {
      float* o = ob + ((size_t)i * 512 + tid) * 3;
      o[0] = pEm; o[1] = pEx; o[2] = pEy;
    }
    if (i >= 2) {   // prefetch: theta/A row ti=i-2, V row i-1
      stage8(thb + (size_t)(i-2)*1536, th_s[(i-2)%3], 6, wid, lane);
      stage8(Ab  + (size_t)(i-2)*4608, A_s[(i-2)%3], 18, wid, lane);
      stage8(Vb  + (size_t)(i-2)*1536, Vls[(i-1)%3], 6, wid, lane);
    }
    const float* thN = th_s[(i-1)%3];  // row ti=i-1 (in-row y successor)
    const float* AN  = A_s[(i-1)%3];
    const float* thK = th_s[i%3];      // row ti=i   (next-row successors; i<512)
    const float* AK  = A_s[i%3];
    const float* Vc  = Vls[i%3];       // V row i
    const float* Vn  = Vls[(i+1)%3];   // V row i+1 (garbage-gated at i=512)
    const float* E1  = Eb[ce ^ 1];
    float* Ec = Eb[ce];
    const int tj = tid;
    const bool hasN = (i < 512);
    const bool hasJ = (tid < 511);
    const int  c1 = hasJ ? tid + 1 : tid;

    float v0 = Vc[tj], v1 = Vc[512 + tj], v2 = Vc[1024 + tj];
    float vyr = hasJ ? Vc[1024 + c1] : 0.f;   // V[i][j+1][y]
    float vnm = Vn[c1];                       // V[i+1][j+1][m]
    float vnx = Vn[512 + tj];                 // V[i+1][j][x]
    float e1m = E1[tid + 2];                  // E[i+1][j+1][m]
    float e1x = E1[514 + tid + 1];            // E[i+1][j][x]
    float thT1 = thK[c1], thT2 = thK[512 + tj], thT3 = thN[1024 + c1];

    float w;
    w = (hasN && hasJ) ? e1m * __expf(v0 + AK[c1]       + thT1 - vnm) : 0.f;
    float D0 = w + (hasN ? e1x * __expf(v0 + AK[1536 + tj] + thT2 - vnx) : 0.f);
    float wy0 = hasJ ? __expf(v0 + AN[3072 + c1] + thT3 - vyr) : 0.f;
    w = (hasN && hasJ) ? e1m * __expf(v1 + AK[512 + c1] + thT1 - vnm) : 0.f;
    float D1 = w + (hasN ? e1x * __expf(v1 + AK[2048 + tj] + thT2 - vnx) : 0.f);
    float wy1 = hasJ ? __expf(v1 + AN[3584 + c1] + thT3 - vyr) : 0.f;
    w = (hasN && hasJ) ? e1m * __expf(v2 + AK[1024 + c1] + thT1 - vnm) : 0.f;
    float D2 = w + (hasN ? e1x * __expf(v2 + AK[2560 + tj] + thT2 - vnx) : 0.f);
    float wy2 = hasJ ? __expf(v2 + AN[4096 + c1] + thT3 - vyr) : 0.f;

    if (i == 512 && tid == 511) {   // terminal softmax seeds the adjoint
      D0 = __expf(v0 - sc); D1 = __expf(v1 - sc); D2 = __expf(v2 - sc);
    }

    // reverse affine scan: E_y[j] = c[j] + r[j]*E_y[j+1]
    float ra = wy2, ca = D2;
    #pragma unroll
    for (int st = 1; st < 64; st <<= 1) {
      float ro = __shfl_down(ra, st, 64);
      float co = __shfl_down(ca, st, 64);
      if (lane + st < 64) { ca = ca + ra * co; ra = ra * ro; }
    }
    if (lane == 0) { wag[wid][0] = ra; wag[wid][1] = ca; }
    bar_raw();
    float sr = 1.f, s2 = 0.f;
    #pragma unroll
    for (int w2 = 0; w2 < 8; ++w2) {
      if (w2 > wid) {
        float2 wv = *(const float2*)&wag[w2][0];
        s2 = s2 + sr * wv.y; sr = sr * wv.x;
      }
    }
    float Ey = ca + ra * s2;
    // E_y[j+1] via shfl_down: lane<63 -> next lane's (ca,ra) with same s2
    // (s2 is wave-uniform); lane 63 -> s2 itself (= next wave's first E_y,
    // by the suffix identity s2[w] = b_agg[w+1] + a_agg[w+1]*s2[w+1]).
    float co2 = __shfl_down(ca, 1, 64);
    float ro2 = __shfl_down(ra, 1, 64);
    float EyR = (lane == 63) ? s2 : (co2 + ro2 * s2);
    float Em = D0 + wy0 * EyR;
    float Ex = D1 + wy1 * EyR;
    Ec[tid + 1] = Em;
    Ec[514 + tid + 1] = Ex;
    pEm = Em; pEx = Ex; pEy = Ey;
    bar_full();
    ce ^= 1;
  }
  // final out store (row 0)
  float* o = ob + (size_t)tid * 3;
  o[0] = pEm; o[1] = pEx; o[2] = pEy;
}

// ---------- launch ----------
extern "C" void kernel_launch(void* const* d_in, const int* in_sizes, int n_in,
                              void* d_out, int out_size, void* d_ws, size_t ws_size,
                              hipStream_t stream) {
  const float* zx = (const float*)d_in[0];
  const float* zy = (const float*)d_in[1];
  const float* gx = (const float*)d_in[2];
  const float* gy = (const float*)d_in[3];
  float* ws = (float*)d_ws;
  float* th = ws;                       // [8][512][3][512]   = 6,291,456 f  (log)
  float* Ag = ws + 6291456;             // [8][512][3v][3u][512] = 18,874,368 f (log)
  float* V  = ws + 25165824;            // [8][512][3][512]   = 6,291,456 f  (log)
  float* sc = ws + 31457280;            // [8]
  float* out = (float*)d_out;           // [8][512][512][3]

  k_gemm_th<<<dim3(8, 8, 8),   256, 0, stream>>>(zx, zy, th);
  k_gemm_A <<<dim3(16, 16, 8), 256, 0, stream>>>(gx, gy, Ag);
  k_fwd<<<8, 512, 0, stream>>>(th, Ag, V, sc);
  k_bwd<<<8, 512, 0, stream>>>(th, Ag, V, sc, out);
}